// Round 2
// baseline (698.711 us; speedup 1.0000x reference)
//
#include <hip/hip_runtime.h>

#define NEGF -1e30f
#define EPSF 1e-7f
#define LN2F 0.69314718055994530942f

// log2-domain logsumexp (v_exp_f32 / v_log_f32 are native 2^x / log2 x).
__device__ __forceinline__ float lse2(float x, float y) {
    float m = fmaxf(x, y);
    return m + log2f(exp2f(x - m) + exp2f(y - m));
}
__device__ __forceinline__ float lse3(float x, float y, float z) {
    float m = fmaxf(fmaxf(x, y), z);
    return m + log2f(exp2f(x - m) + exp2f(y - m) + exp2f(z - m));
}

// CTC forward NLL, blank = C-1, full lengths. One wave64 per batch element.
// Lane l owns extended states 4l..4l+3; lane 63 also owns state 256 (reg a4,
// computed redundantly on all lanes to avoid divergence).
// Even states (blank) never take the s-2 skip, so the only cross-lane value
// per step is alpha[4l-1] -> ONE __shfl_up. Per-frame log-probs are gathered
// straight from global memory 8 steps ahead into a statically-indexed
// register ring (labels are static per batch) -> no LDS, no barriers.
__global__ __launch_bounds__(64)
void ctc_fwd_wave(const int* __restrict__ y_true,
                  const float* __restrict__ y_pred,
                  float* __restrict__ out,
                  int T, int C, int L) {
    const int b = blockIdx.x;
    const int l = threadIdx.x;           // lane 0..63
    const float* Yb = y_pred + (size_t)b * T * C;
    const int*   lb = y_true + (size_t)b * L;

    // Labels owned by this lane: states 4l+1 -> lb[2l], 4l+3 -> lb[2l+1].
    const int lab0 = lb[2 * l];
    const int lab1 = lb[2 * l + 1];
    const int labP = __shfl_up(lab1, 1); // label[2l-1] (prev lane)
    const bool sk1 = (l > 0) && (lab0 != labP);  // s=4l+1 skip (s>=3 => l>=1)
    const bool sk3 = (lab1 != lab0);             // s=4l+3 skip
    const int cb = C - 1;

    // alpha_0: only states 0 (blank) and 1 (label 0) are live.
    float a0, a1, a2 = NEGF, a3 = NEGF, a4 = NEGF;
    {
        const float pb = Yb[cb];
        const float p0 = Yb[lab0];
        a0 = (l == 0) ? log2f(pb + EPSF) : NEGF;
        a1 = (l == 0) ? log2f(p0 + EPSF) : NEGF;
    }

    // 8-deep prefetch ring of raw probs (slot = t & 7), statically indexed.
    float rb_[8], r0_[8], r1_[8];
#pragma unroll
    for (int k = 1; k <= 8; ++k) {
        const int s = k & 7;
        if (k < T) {
            const float* rp = Yb + (size_t)k * C;
            rb_[s] = rp[cb];
            r0_[s] = rp[lab0];
            r1_[s] = rp[lab1];
        }
    }

#define CTC_STEP(S, TCUR)                                                   \
    do {                                                                    \
        float pm1 = __shfl_up(a3, 1);     /* alpha[4l-1] from prev lane */  \
        if (l == 0) pm1 = NEGF;                                             \
        const float lpb = log2f(rb_[S] + EPSF);                             \
        const float lp0 = log2f(r0_[S] + EPSF);                             \
        const float lp1 = log2f(r1_[S] + EPSF);                             \
        if ((TCUR) + 8 < T) {             /* refill slot for t+8 */         \
            const float* rp = Yb + (size_t)((TCUR) + 8) * C;                \
            rb_[S] = rp[cb];                                                \
            r0_[S] = rp[lab0];                                              \
            r1_[S] = rp[lab1];                                              \
        }                                                                   \
        const float n0 = lse2(a0, pm1) + lpb;                               \
        const float n1 = lse3(a1, a0, sk1 ? pm1 : NEGF) + lp0;              \
        const float n2 = lse2(a2, a1) + lpb;                                \
        const float n3 = lse3(a3, a2, sk3 ? a1 : NEGF) + lp1;               \
        const float n4 = lse2(a4, a3) + lpb; /* state 256, lane 63 */       \
        a0 = n0; a1 = n1; a2 = n2; a3 = n3; a4 = n4;                        \
    } while (0)

    int tb = 1;
    // Main loop: tb ≡ 1 (mod 8) -> slot for t = tb+i is (1+i)&7, static.
    for (; tb + 8 <= T; tb += 8) {
#pragma unroll
        for (int i = 0; i < 8; ++i) {
            const int s = (1 + i) & 7;
            CTC_STEP(s, tb + i);
        }
    }
    // Tail: < 8 remaining steps, same static slot pattern, guarded.
#pragma unroll
    for (int i = 0; i < 7; ++i) {
        const int s = (1 + i) & 7;
        if (tb + i < T) {
            CTC_STEP(s, tb + i);
        }
    }
#undef CTC_STEP

    if (l == 63) {
        // loss = -ln P = -ln2 * log2addexp(alpha_T[256], alpha_T[255])
        out[b] = -LN2F * lse2(a4, a3);
    }
}

extern "C" void kernel_launch(void* const* d_in, const int* in_sizes, int n_in,
                              void* d_out, int out_size, void* d_ws, size_t ws_size,
                              hipStream_t stream) {
    const int*   y_true = (const int*)d_in[0];
    const float* y_pred = (const float*)d_in[1];
    float*       out    = (float*)d_out;

    const int B = out_size;               // 512
    const int L = in_sizes[0] / B;        // 128
    const int C = 256;                    // channels (blank = C-1)
    const int T = in_sizes[1] / (B * C);  // 512

    ctc_fwd_wave<<<B, 64, 0, stream>>>(y_true, y_pred, out, T, C, L);
}

// Round 3
// 433.249 us; speedup vs baseline: 1.6127x; 1.6127x over previous
//
#include <hip/hip_runtime.h>

#define NEGF -1e30f
#define EPSF 1e-7f
#define LN2F 0.69314718055994530942f
#define DPRE 16   // LDS row-ring depth; vmcnt literals below assume 16

// log2-domain logsumexp (native v_exp_f32 / v_log_f32)
__device__ __forceinline__ float lse2(float x, float y) {
    float m = fmaxf(x, y);
    return m + log2f(exp2f(x - m) + exp2f(y - m));
}
__device__ __forceinline__ float lse3(float x, float y, float z) {
    float m = fmaxf(fmaxf(x, y), z);   // -> v_max3_f32
    return m + log2f(exp2f(x - m) + exp2f(y - m) + exp2f(z - m));
}

// DPP whole-wave shifts (VALU-only cross-lane; keeps lgkmcnt clean for LDS prefetch)
// lane i <- lane i-1, lane 0 <- fill   (== __shfl_up(v,1))
__device__ __forceinline__ float wshr1(float v, float fill) {
    return __int_as_float(__builtin_amdgcn_update_dpp(
        __float_as_int(fill), __float_as_int(v), 0x138, 0xf, 0xf, false));
}
// lane i <- lane i+1, lane 63 <- fill  (== __shfl_down(v,1))
__device__ __forceinline__ float wshl1(float v, float fill) {
    return __int_as_float(__builtin_amdgcn_update_dpp(
        __float_as_int(fill), __float_as_int(v), 0x130, 0xf, 0xf, false));
}

typedef const __attribute__((address_space(1))) void* gptr_t;
typedef __attribute__((address_space(3))) void* lptr_t;
// One instruction stages a whole 1KB row: 64 lanes x 16B, LDS dst = uniform base + lane*16
__device__ __forceinline__ void gload_row(const float* src, float* dst) {
    __builtin_amdgcn_global_load_lds((gptr_t)src, (lptr_t)dst, 16, 0, 0);
}

// CTC fwd-bwd meet-in-the-middle. One block = one batch element = 2 waves.
// Wave 0: alpha over frames 0..kf. Wave 1: beta over frames T-1..kf+1.
// Lane l owns extended states 4l..4l+3 (+ state 256 on lane 63).
// loss = -ln2 * lse_s(alpha_kf[s] + beta_kf[s]).
__global__ __launch_bounds__(128)
void ctc_fb(const int* __restrict__ y_true,
            const float* __restrict__ y_pred,
            float* __restrict__ out,
            int T, int L) {
    const int C = 256, cb = 255;
    const int b   = blockIdx.x;
    const int tid = threadIdx.x;
    const int w   = tid >> 6;     // 0 = forward, 1 = backward
    const int l   = tid & 63;
    const int kf  = T >> 1;       // meet frame

    __shared__ float buf[2][DPRE][256];
    __shared__ float comb[260];

    const float* Yb = y_pred + (size_t)b * T * C;
    const int*   lb = y_true + (size_t)b * L;

    const int  lab0 = lb[2 * l];
    const int  lab1 = lb[2 * l + 1];
    const int  labP = __shfl_up(lab1, 1);
    const bool sk1  = (l > 0) && (lab0 != labP);   // skip into state 4l+1
    const bool sk3  = (lab1 != lab0);              // skip into state 4l+3
    const bool skD  = (l < 63) && (__shfl_down(sk1 ? 1 : 0, 1) != 0); // skip into 4l+5

    float r0 = NEGF, r1 = NEGF, r2 = NEGF, r3 = NEGF, r4 = NEGF;

    if (w == 0) {
        // ---------------- forward: frames 0..kf ----------------
        for (int k = 0; k < DPRE; ++k)
            gload_row(Yb + (size_t)k * C + 4 * l, &buf[0][k][0]);
        asm volatile("s_waitcnt vmcnt(15)" ::: "memory");   // frame 0 in LDS
        float vb = buf[0][0][cb];
        float v0 = buf[0][0][lab0];
        r0 = (l == 0) ? log2f(vb + EPSF) : NEGF;
        r1 = (l == 0) ? log2f(v0 + EPSF) : NEGF;
        asm volatile("s_waitcnt vmcnt(14)" ::: "memory");   // frame 1 in LDS
        vb = buf[0][1][cb]; v0 = buf[0][1][lab0];
        float v1 = buf[0][1][lab1];

        for (int i = 0; i < kf; ++i) {
            // consume frame i+1 (in regs), prefetch frame i+2's gathers
            const float lpb = log2f(vb + EPSF);
            const float lp0 = log2f(v0 + EPSF);
            const float lp1 = log2f(v1 + EPSF);
            const int fn = DPRE + i;
            if (fn <= kf)
                gload_row(Yb + (size_t)fn * C + 4 * l, &buf[0][fn & (DPRE - 1)][0]);
            asm volatile("s_waitcnt vmcnt(14)" ::: "memory"); // frame i+2 in LDS
            const int sl = (i + 2) & (DPRE - 1);
            const float nvb = buf[0][sl][cb];
            const float nv0 = buf[0][sl][lab0];
            const float nv1 = buf[0][sl][lab1];

            const float pm1 = wshr1(r3, NEGF);              // alpha[4l-1]
            const float n0 = lse2(r0, pm1) + lpb;
            const float n1 = lse3(r1, r0, sk1 ? pm1 : NEGF) + lp0;
            const float n2 = lse2(r2, r1) + lpb;
            const float n3 = lse3(r3, r2, sk3 ? r1 : NEGF) + lp1;
            const float n4 = lse2(r4, r3) + lpb;            // state 256
            r0 = n0; r1 = n1; r2 = n2; r3 = n3; r4 = n4;
            vb = nvb; v0 = nv0; v1 = nv1;
        }
        // publish alpha_kf
        *(float4*)&comb[4 * l] = make_float4(r0, r1, r2, r3);
        if (l == 63) comb[256] = r4;
    } else {
        // ---------------- backward: frames T-1..kf+1 ----------------
        for (int k = 0; k < DPRE; ++k) {
            const int f = T - 1 - k;
            gload_row(Yb + (size_t)f * C + 4 * l, &buf[1][f & (DPRE - 1)][0]);
        }
        r3 = (l == 63) ? 0.0f : NEGF;   // beta_T: states 255,256
        r4 = (l == 63) ? 0.0f : NEGF;
        asm volatile("s_waitcnt vmcnt(15)" ::: "memory");   // frame T-1 in LDS
        const int s0i = (T - 1) & (DPRE - 1);
        float vb = buf[1][s0i][cb];
        float v0 = buf[1][s0i][lab0];
        float v1 = buf[1][s0i][lab1];

        const int NB = T - 1 - kf;
        for (int j = 0; j < NB; ++j) {
            // consume frame T-1-j (in regs), prefetch frame T-2-j
            const float lpb = log2f(vb + EPSF);
            const float lp0 = log2f(v0 + EPSF);
            const float lp1 = log2f(v1 + EPSF);
            const int fn = T - 1 - (DPRE + j);
            if (fn > kf)
                gload_row(Yb + (size_t)fn * C + 4 * l, &buf[1][fn & (DPRE - 1)][0]);
            asm volatile("s_waitcnt vmcnt(15)" ::: "memory"); // frame T-2-j in LDS
            const int sl = (T - 2 - j) & (DPRE - 1);
            const float nvb = buf[1][sl][cb];
            const float nv0 = buf[1][sl][lab0];
            const float nv1 = buf[1][sl][lab1];

            const float c0 = r0 + lpb;
            const float c1 = r1 + lp0;
            const float c2 = r2 + lpb;
            const float c3 = r3 + lp1;
            const float c4 = r4 + lpb;                      // state 256
            float d0 = wshl1(c0, NEGF);                     // c[4l+4]
            const float d1 = wshl1(c1, NEGF);               // c[4l+5]
            if (l == 63) d0 = c4;                           // state 255 -> 256
            const float n0 = lse2(c0, c1);
            const float n1 = lse3(c1, c2, sk3 ? c3 : NEGF);
            const float n2 = lse2(c2, c3);
            const float n3 = lse3(c3, d0, skD ? d1 : NEGF);
            r0 = n0; r1 = n1; r2 = n2; r3 = n3; r4 = c4;
            vb = nvb; v0 = nv0; v1 = nv1;
        }
    }
    __syncthreads();

    if (w == 1) {
        // P = lse_s(alpha[s] + beta[s]); reduce across the wave
        const float4 av = *(const float4*)&comb[4 * l];
        const float s0 = av.x + r0, s1 = av.y + r1;
        const float s2 = av.z + r2, s3 = av.w + r3;
        const float s4 = (l == 63) ? (comb[256] + r4) : NEGF;
        float m = fmaxf(fmaxf(fmaxf(s0, s1), fmaxf(s2, s3)), s4);
        for (int o = 32; o; o >>= 1) m = fmaxf(m, __shfl_xor(m, o));
        float p = exp2f(s0 - m) + exp2f(s1 - m) + exp2f(s2 - m)
                + exp2f(s3 - m) + exp2f(s4 - m);
        for (int o = 32; o; o >>= 1) p += __shfl_xor(p, o);
        if (l == 0) out[b] = -LN2F * (m + log2f(p));
    }
}

extern "C" void kernel_launch(void* const* d_in, const int* in_sizes, int n_in,
                              void* d_out, int out_size, void* d_ws, size_t ws_size,
                              hipStream_t stream) {
    const int*   y_true = (const int*)d_in[0];
    const float* y_pred = (const float*)d_in[1];
    float*       out    = (float*)d_out;

    const int B = out_size;               // 512
    const int L = in_sizes[0] / B;        // 128
    const int C = 256;                    // channels (blank = C-1)
    const int T = in_sizes[1] / (B * C);  // 512

    ctc_fb<<<B, 128, 0, stream>>>(y_true, y_pred, out, T, L);
}